// Round 1
// baseline (705.614 us; speedup 1.0000x reference)
//
#include <hip/hip_runtime.h>
#include <math.h>

#define B_ 16
#define L_ 512
#define H_ 8
#define E_ 64
#define ROWS 16

// ---------------- Kernel 1: sigma transform ----------------
// sig = 3^(sigmoid(5x)+1e-5) - 1, laid out [B,H,L] in workspace.
__global__ void sig_kernel(const float* __restrict__ sigma, float* __restrict__ sig_ws) {
    int o = blockIdx.x * blockDim.x + threadIdx.x;  // index over [B,H,L]
    if (o >= B_ * H_ * L_) return;
    int l = o % L_;
    int h = (o / L_) % H_;
    int b = o / (L_ * H_);
    float x = sigma[(size_t)(b * L_ + l) * H_ + h];
    float s = 1.0f / (1.0f + expf(-5.0f * x)) + 1e-5f;
    float sg = exp2f(s * 1.5849625007211562f) - 1.0f;  // 3^s - 1
    sig_ws[o] = sg;
}

// ---------------- Kernel 2: prior + sigma_full ----------------
// One block per (b,h,l) row; streams out 2 * 512 floats.
__global__ void prior_kernel(const float* __restrict__ sig_ws,
                             float* __restrict__ prior,
                             float* __restrict__ sigma_full) {
    int row = blockIdx.x;   // over [B,H,L]
    int l = row % L_;
    float sg = sig_ws[row];
    float inv = 0.3989422804014327f / sg;   // 1/sqrt(2*pi) / sig
    float coef = -0.5f / (sg * sg);
    size_t base = (size_t)row * L_;
    for (int j = threadIdx.x; j < L_; j += 256) {
        float d = (float)(l > j ? l - j : j - l);
        float p = inv * expf(coef * d * d);
        prior[base + j] = p;
        sigma_full[base + j] = sg;
    }
}

// ---------------- Kernel 3: fused attention ----------------
// One block per (b, h, 16-row slab). 256 threads.
// LDS: Q slab (4KB) + score tile 16x512 f32 (32KB).
__launch_bounds__(256, 4)
__global__ void attn_kernel(const float* __restrict__ Q,
                            const float* __restrict__ K,
                            const float* __restrict__ V,
                            float* __restrict__ Vout,
                            float* __restrict__ series) {
    __shared__ float Qs[ROWS][E_];
    __shared__ float S[ROWS][L_];
    __shared__ float rowred[ROWS];

    int bid = blockIdx.x;
    int rb = bid % (L_ / ROWS);
    int bh = bid / (L_ / ROWS);
    int h = bh % H_;
    int b = bh / H_;
    int l0 = rb * ROWS;
    int t = threadIdx.x;

    // ---- stage Q slab: 16 rows x 64 elems ----
    const float* qbase = Q + ((size_t)(b * L_ + l0) * H_ + h) * E_;
    #pragma unroll
    for (int i = 0; i < (ROWS * E_) / 256; ++i) {   // 4 iters
        int flat = i * 256 + t;
        int r = flat >> 6, e = flat & 63;
        Qs[r][e] = qbase[(size_t)r * (H_ * E_) + e];
    }
    __syncthreads();

    // ---- scores: thread t owns columns t and t+256 ----
    const float* kb = K + ((size_t)b * L_ * H_ + h) * E_;
    float acc0[ROWS], acc1[ROWS];
    #pragma unroll
    for (int r = 0; r < ROWS; ++r) { acc0[r] = 0.0f; acc1[r] = 0.0f; }
    int c0 = t, c1 = t + 256;
    const float4* k0 = (const float4*)(kb + (size_t)c0 * (H_ * E_));
    const float4* k1 = (const float4*)(kb + (size_t)c1 * (H_ * E_));
    for (int e4 = 0; e4 < E_ / 4; ++e4) {
        float4 kv0 = k0[e4];
        float4 kv1 = k1[e4];
        int e = e4 * 4;
        #pragma unroll
        for (int r = 0; r < ROWS; ++r) {
            acc0[r] += Qs[r][e + 0] * kv0.x + Qs[r][e + 1] * kv0.y
                     + Qs[r][e + 2] * kv0.z + Qs[r][e + 3] * kv0.w;
            acc1[r] += Qs[r][e + 0] * kv1.x + Qs[r][e + 1] * kv1.y
                     + Qs[r][e + 2] * kv1.z + Qs[r][e + 3] * kv1.w;
        }
    }
    #pragma unroll
    for (int r = 0; r < ROWS; ++r) {
        S[r][c0] = acc0[r] * 0.125f;   // scale = 1/sqrt(64)
        S[r][c1] = acc1[r] * 0.125f;
    }
    __syncthreads();

    // ---- softmax: 16 threads per row (sr = t>>4, g = t&15) ----
    int sr = t >> 4, g = t & 15;
    float m = -INFINITY;
    for (int k = 0; k < 32; ++k) m = fmaxf(m, S[sr][g + 16 * k]);
    #pragma unroll
    for (int off = 8; off >= 1; off >>= 1) m = fmaxf(m, __shfl_xor(m, off, 16));
    float sum = 0.0f;
    for (int k = 0; k < 32; ++k) {
        float e = expf(S[sr][g + 16 * k] - m);
        S[sr][g + 16 * k] = e;
        sum += e;
    }
    #pragma unroll
    for (int off = 8; off >= 1; off >>= 1) sum += __shfl_xor(sum, off, 16);
    if (g == 0) rowred[sr] = 1.0f / sum;
    __syncthreads();

    // ---- normalize + write series (coalesced by column ownership) ----
    size_t sbase = ((size_t)(b * H_ + h) * L_ + l0) * L_;
    #pragma unroll
    for (int r = 0; r < ROWS; ++r) {
        float is = rowred[r];
        float p0 = S[r][c0] * is;
        float p1 = S[r][c1] * is;
        S[r][c0] = p0;
        S[r][c1] = p1;
        series[sbase + (size_t)r * L_ + c0] = p0;
        series[sbase + (size_t)r * L_ + c1] = p1;
    }
    __syncthreads();

    // ---- PV: thread owns (d = t&63, rows rq*4 .. rq*4+3) ----
    int d = t & 63;
    int rq = t >> 6;
    float vacc[4] = {0.0f, 0.0f, 0.0f, 0.0f};
    const float* vb = V + ((size_t)b * L_ * H_ + h) * E_ + d;
    for (int s = 0; s < L_; ++s) {
        float vv = vb[(size_t)s * (H_ * E_)];
        #pragma unroll
        for (int i = 0; i < 4; ++i) {
            vacc[i] += S[rq * 4 + i][s] * vv;   // LDS broadcast read
        }
    }
    #pragma unroll
    for (int i = 0; i < 4; ++i) {
        int r = rq * 4 + i;
        Vout[((size_t)(b * L_ + l0 + r) * H_ + h) * E_ + d] = vacc[i];
    }
}

extern "C" void kernel_launch(void* const* d_in, const int* in_sizes, int n_in,
                              void* d_out, int out_size, void* d_ws, size_t ws_size,
                              hipStream_t stream) {
    const float* queries = (const float*)d_in[0];
    const float* keys    = (const float*)d_in[1];
    const float* values  = (const float*)d_in[2];
    const float* sigma   = (const float*)d_in[3];
    // d_in[4] = attn_mask (unused, mask_flag=False)

    float* out = (float*)d_out;
    const size_t nV = (size_t)B_ * L_ * H_ * E_;        // 4,194,304
    const size_t nS = (size_t)B_ * H_ * L_ * L_;        // 33,554,432
    float* Vout       = out;
    float* series     = out + nV;
    float* prior      = out + nV + nS;
    float* sigma_full = out + nV + 2 * nS;

    float* sig_ws = (float*)d_ws;  // B*H*L floats = 256 KB

    // 1) sigma transform
    sig_kernel<<<(B_ * H_ * L_ + 255) / 256, 256, 0, stream>>>(sigma, sig_ws);
    // 2) prior + sigma_full (pure streaming writes)
    prior_kernel<<<B_ * H_ * L_, 256, 0, stream>>>(sig_ws, prior, sigma_full);
    // 3) fused attention: scores -> softmax -> series + PV
    attn_kernel<<<B_ * H_ * (L_ / ROWS), 256, 0, stream>>>(queries, keys, values,
                                                           Vout, series);
}

// Round 2
// 535.182 us; speedup vs baseline: 1.3185x; 1.3185x over previous
//
#include <hip/hip_runtime.h>
#include <hip/hip_bf16.h>
#include <math.h>

#define B_ 16
#define L_ 512
#define H_ 8
#define E_ 64

typedef float f32x4 __attribute__((ext_vector_type(4)));
typedef short bf16x8 __attribute__((ext_vector_type(8)));
typedef short s16x4 __attribute__((ext_vector_type(4)));
typedef unsigned int u32x2 __attribute__((ext_vector_type(2)));
typedef unsigned int u32x4 __attribute__((ext_vector_type(4)));

__device__ __forceinline__ short f2bf(float f) {
    __hip_bfloat16 h = __float2bfloat16(f);   // RNE; compiler pairs into v_cvt_pk_bf16_f32
    return __builtin_bit_cast(short, h);
}

__device__ __forceinline__ bf16x8 cvt8(const float* p) {
    f32x4 a = *(const f32x4*)p;
    f32x4 b = *(const f32x4*)(p + 4);
    bf16x8 r;
    r[0] = f2bf(a[0]); r[1] = f2bf(a[1]); r[2] = f2bf(a[2]); r[3] = f2bf(a[3]);
    r[4] = f2bf(b[0]); r[5] = f2bf(b[1]); r[6] = f2bf(b[2]); r[7] = f2bf(b[3]);
    return r;
}

// ---------------- Kernel 1: V -> V^T bf16 (into sigma_full slot as scratch) ----
// Vt[(bh*64 + d)*512 + s] = bf16(V[b][s][h][d]).  Grid: B*H*8 blocks, 256 thr.
__global__ void vt_kernel(const float* __restrict__ V, unsigned short* __restrict__ Vt) {
    __shared__ float tile[64][68];
    int bid = blockIdx.x;
    int sc = bid & 7, bh = bid >> 3;
    int h = bh & 7, b = bh >> 3;
    int t = threadIdx.x;
    int s0 = sc * 64;
    const float* vb = V + ((size_t)b * 512 + s0) * 512 + h * 64;
    #pragma unroll
    for (int i = 0; i < 4; ++i) {
        int srow = i * 16 + (t >> 4);
        int d4 = (t & 15) * 4;
        f32x4 v = *(const f32x4*)(vb + (size_t)srow * 512 + d4);
        tile[srow][d4 + 0] = v[0]; tile[srow][d4 + 1] = v[1];
        tile[srow][d4 + 2] = v[2]; tile[srow][d4 + 3] = v[3];
    }
    __syncthreads();
    int d = t >> 2, c = t & 3;
    unsigned us[8];
    #pragma unroll
    for (int k = 0; k < 8; ++k) {
        unsigned lo = (unsigned short)f2bf(tile[c * 16 + 2 * k][d]);
        unsigned hi = (unsigned short)f2bf(tile[c * 16 + 2 * k + 1][d]);
        us[k] = lo | (hi << 16);
    }
    unsigned short* dst = Vt + ((size_t)bh * 64 + d) * 512 + s0 + c * 16;
    *(u32x4*)dst       = u32x4{us[0], us[1], us[2], us[3]};
    *(u32x4*)(dst + 8) = u32x4{us[4], us[5], us[6], us[7]};
}

// ---------------- Kernel 2: fused MFMA attention ----------------
// Block = 4 waves; wave owns 16 q-rows x all 512 keys. No __syncthreads needed.
#define PSTR 544                       // bf16 row stride for P tile
#define WLDS (16 * PSTR * 2 + 64)      // per-wave LDS bytes (17472, 16B-divisible)

__launch_bounds__(256, 2)
__global__ void attn_kernel(const float* __restrict__ Qg,
                            const float* __restrict__ Kg,
                            const unsigned short* __restrict__ Vt,
                            float* __restrict__ Vout,
                            float* __restrict__ series) {
    __shared__ __align__(16) char lds[4 * WLDS];
    int tid = threadIdx.x;
    int w = tid >> 6, l = tid & 63;
    int lm = l & 15, g = l >> 4;

    int bid = blockIdx.x;
    int nid = (bid & 7) * 128 + (bid >> 3);   // XCD-aware bijective swizzle (1024 % 8 == 0)
    int rb = nid & 7, bh = nid >> 3;
    int h = bh & 7, b = bh >> 3;
    int l0 = rb * 64 + w * 16;                // wave's q-row base

    char* wl = lds + w * WLDS;

    // ---- Q B-fragments (2 k-steps over E=64) ----
    const float* qrow = Qg + ((size_t)b * 512 + l0 + lm) * 512 + h * 64;
    bf16x8 qf0 = cvt8(qrow + g * 8);
    bf16x8 qf1 = cvt8(qrow + 32 + g * 8);

    // ---- QK^T (transposed): acc[t] holds St[s=16t+4g+r][q=lm] ----
    const float* krow0 = Kg + (size_t)b * 512 * 512 + (size_t)lm * 512 + h * 64 + g * 8;
    f32x4 acc[32];
    #pragma unroll
    for (int t = 0; t < 32; ++t) acc[t] = 0.0f;
    #pragma unroll
    for (int t = 0; t < 32; ++t) {
        const float* kr = krow0 + (size_t)t * 16 * 512;
        bf16x8 kf0 = cvt8(kr);
        bf16x8 kf1 = cvt8(kr + 32);
        acc[t] = __builtin_amdgcn_mfma_f32_16x16x32_bf16(kf0, qf0, acc[t], 0, 0, 0);
        acc[t] = __builtin_amdgcn_mfma_f32_16x16x32_bf16(kf1, qf1, acc[t], 0, 0, 0);
    }

    // ---- softmax over s (per lane: 128 raw scores for q=lm) ----
    float m = -1e30f;
    #pragma unroll
    for (int t = 0; t < 32; ++t)
        m = fmaxf(m, fmaxf(fmaxf(acc[t][0], acc[t][1]), fmaxf(acc[t][2], acc[t][3])));
    m = fmaxf(m, __shfl_xor(m, 16));
    m = fmaxf(m, __shfl_xor(m, 32));
    const float SC = 0.125f * 1.44269504088896340736f;   // scale * log2(e)
    float ssum = 0.0f;
    #pragma unroll
    for (int t = 0; t < 32; ++t) {
        #pragma unroll
        for (int r = 0; r < 4; ++r) {
            float p = exp2f((acc[t][r] - m) * SC);
            acc[t][r] = p;
            ssum += p;
        }
    }
    ssum += __shfl_xor(ssum, 16);
    ssum += __shfl_xor(ssum, 32);
    float inv = 1.0f / ssum;                 // inv-sum for q = lm (all lanes)

    // ---- write P (bf16, unnormalized) to swizzled per-wave LDS ----
    #pragma unroll
    for (int t = 0; t < 32; ++t) {
        s16x4 pw;
        pw[0] = f2bf(acc[t][0]); pw[1] = f2bf(acc[t][1]);
        pw[2] = f2bf(acc[t][2]); pw[3] = f2bf(acc[t][3]);
        int off = (lm * (PSTR * 2) + (t * 16 + g * 4) * 2) ^ ((lm & 7) << 4);
        *(s16x4*)(wl + off) = pw;
    }

    // ---- PV: O^T[d][q] = sum_s V^T[d][s] * P^T[s][q] ----
    f32x4 oacc[4];
    #pragma unroll
    for (int dt = 0; dt < 4; ++dt) oacc[dt] = 0.0f;
    const unsigned short* vtb = Vt + ((size_t)bh * 64 + lm) * 512;
    #pragma unroll
    for (int ks = 0; ks < 16; ++ks) {
        int poff = (lm * (PSTR * 2) + (ks * 32 + g * 8) * 2) ^ ((lm & 7) << 4);
        bf16x8 pb = *(const bf16x8*)(wl + poff);
        #pragma unroll
        for (int dt = 0; dt < 4; ++dt) {
            bf16x8 va = *(const bf16x8*)(vtb + (size_t)dt * 16 * 512 + ks * 32 + g * 8);
            oacc[dt] = __builtin_amdgcn_mfma_f32_16x16x32_bf16(va, pb, oacc[dt], 0, 0, 0);
        }
    }

    // ---- series write: normalized, coalesced float4 (reads P back from LDS) ----
    float isq = __shfl(inv, l >> 2);         // lanes 0..15 hold inv for q=0..15
    size_t srow = ((size_t)bh * 512 + l0 + (l >> 2)) * 512;
    int pbase = ((l >> 2) * (PSTR * 2));
    int pswz = (((l >> 2) & 7) << 4);
    #pragma unroll
    for (int j = 0; j < 32; ++j) {
        int s = j * 16 + (l & 3) * 4;
        u32x2 pk = *(const u32x2*)(wl + ((pbase + s * 2) ^ pswz));
        f32x4 o;
        o[0] = __uint_as_float(pk[0] << 16) * isq;
        o[1] = __uint_as_float(pk[0] & 0xffff0000u) * isq;
        o[2] = __uint_as_float(pk[1] << 16) * isq;
        o[3] = __uint_as_float(pk[1] & 0xffff0000u) * isq;
        *(f32x4*)(series + srow + s) = o;
    }

    // ---- Vout via LDS transpose (reuse P region; P dead now) ----
    float* Olds = (float*)wl;                // [64 d][17 q] f32 = 4352B
    #pragma unroll
    for (int dt = 0; dt < 4; ++dt)
        #pragma unroll
        for (int r = 0; r < 4; ++r)
            Olds[(dt * 16 + g * 4 + r) * 17 + lm] = oacc[dt][r] * inv;
    #pragma unroll
    for (int it = 0; it < 4; ++it) {
        int rr = it * 4 + g;
        f32x4 o;
        #pragma unroll
        for (int e = 0; e < 4; ++e) o[e] = Olds[(lm * 4 + e) * 17 + rr];
        *(f32x4*)(Vout + ((size_t)b * 512 + l0 + rr) * 512 + h * 64 + lm * 4) = o;
    }
}

// ---------------- Kernel 3: prior + sigma_full (fused sigma transform) --------
// 4 rows per block, 64 lanes/row, 8 elems/lane, all float4 stores.
__global__ void prior_kernel(const float* __restrict__ sigma,
                             float* __restrict__ prior,
                             float* __restrict__ sigf) {
    int t = threadIdx.x;
    int row = blockIdx.x * 4 + (t >> 6);      // over [B*H*L]
    int l = row & 511, bh = row >> 9;
    int h = bh & 7, b = bh >> 3;
    float x = sigma[((size_t)b * 512 + l) * 8 + h];
    float s = 1.0f / (1.0f + exp2f(-7.2134752044448170368f * x)) + 1e-5f; // sigmoid(5x)
    float sg = exp2f(s * 1.5849625007211562f) - 1.0f;                     // 3^s - 1
    float invc = 0.3989422804014327f / sg;
    float c2 = -0.72134752044448170368f / (sg * sg);                      // -log2e/(2 sg^2)
    int c = t & 63;
    size_t base = (size_t)row * 512 + c * 8;
    f32x4 p0, p1, sv;
    #pragma unroll
    for (int k = 0; k < 4; ++k) {
        float d0 = (float)(l - (c * 8 + k));
        float d1 = (float)(l - (c * 8 + 4 + k));
        p0[k] = invc * exp2f(c2 * d0 * d0);
        p1[k] = invc * exp2f(c2 * d1 * d1);
        sv[k] = sg;
    }
    *(f32x4*)(prior + base)     = p0;
    *(f32x4*)(prior + base + 4) = p1;
    *(f32x4*)(sigf + base)      = sv;
    *(f32x4*)(sigf + base + 4)  = sv;
}

extern "C" void kernel_launch(void* const* d_in, const int* in_sizes, int n_in,
                              void* d_out, int out_size, void* d_ws, size_t ws_size,
                              hipStream_t stream) {
    const float* queries = (const float*)d_in[0];
    const float* keys    = (const float*)d_in[1];
    const float* values  = (const float*)d_in[2];
    const float* sigma   = (const float*)d_in[3];

    float* out = (float*)d_out;
    const size_t nV = (size_t)B_ * L_ * H_ * E_;     // 4,194,304
    const size_t nS = (size_t)B_ * H_ * L_ * L_;     // 33,554,432
    float* Vout       = out;
    float* series     = out + nV;
    float* prior      = out + nV + nS;
    float* sigma_full = out + nV + 2 * nS;

    // Scratch: V^T bf16 (16.8 MB) lives in the sigma_full slot until prior_kernel
    // overwrites it (stream-ordered after attn).
    unsigned short* Vt = (unsigned short*)sigma_full;

    vt_kernel<<<B_ * H_ * 8, 256, 0, stream>>>(values, Vt);
    attn_kernel<<<B_ * H_ * 8, 256, 0, stream>>>(queries, keys, Vt, Vout, series);
    prior_kernel<<<B_ * H_ * L_ / 4, 256, 0, stream>>>(sigma, prior, sigma_full);
}